// Round 11
// baseline (420.016 us; speedup 1.0000x reference)
//
#include <hip/hip_runtime.h>
#include <stdint.h>

#define BATCH 16
#define CIN   32
#define HH    128
#define WW    128
#define BO    32
#define OCH   128   // 4*BO
#define NCH   8     // h-chunks (16 rows each)
#define RPC   16
#define DEPTH 64    // handoff ring depth

// ws: [0,4096) progress ints
//     [4096, +RINGSZ) tagged handoff ring
//     [4096+RINGSZ, +I2SHSZ) i2s buffer (f16, layout [b][t][row][o])
#define RINGSZ ((size_t)BATCH * NCH * DEPTH * BO * 8)
#define I2SHSZ ((size_t)BATCH * WW * HH * OCH * 2)

typedef _Float16 f16x4v __attribute__((ext_vector_type(4)));
typedef _Float16 f16x8v __attribute__((ext_vector_type(8)));
typedef float    f32x4v __attribute__((ext_vector_type(4)));

// ===== K1: i2s_h[b][t][row][o] = (f16)(b2+b1 + sum_c W2[o][c]*xskew) ========
__global__ __launch_bounds__(256, 4) void i2s_gemm_h(
    const float* __restrict__ x, const float* __restrict__ W2g,
    const float* __restrict__ b2, const float* __restrict__ b1,
    _Float16* __restrict__ i2sh)
{
    const int tid = threadIdx.x;
    const int bx  = blockIdx.x;
    const int b   = bx >> 7;
    const int row = bx & 127;

    __shared__ __attribute__((aligned(16))) float xs[CIN][WW];
    __shared__ __attribute__((aligned(16))) float w2s[CIN][OCH];
    __shared__ float bs[OCH];

    for (int i = tid; i < CIN * OCH; i += 256) {
        const int c = i >> 7, o = i & 127;
        w2s[c][o] = W2g[o * CIN + c];
    }
    if (tid < OCH) bs[tid] = b2[tid] + b1[tid];
    for (int i = tid; i < CIN * WW; i += 256) {
        const int c = i >> 7, t = i & 127;
        xs[c][t] = (t >= row)
            ? x[((size_t)(b * CIN + c) * HH + row) * WW + (t - row)] : 0.f;
    }
    __syncthreads();

    const int tm = tid >> 4;
    const int tn = tid & 15;
    const int t0 = tm * 8, o0 = tn * 8;

    float bv[8];
    *(float4*)&bv[0] = *(const float4*)&bs[o0];
    *(float4*)&bv[4] = *(const float4*)&bs[o0 + 4];
    float acc[8][8];
#pragma unroll
    for (int i = 0; i < 8; ++i)
#pragma unroll
        for (int jj = 0; jj < 8; ++jj) acc[i][jj] = bv[jj];

    for (int c = 0; c < CIN; ++c) {
        float a[8], wv[8];
        *(float4*)&a[0]  = *(const float4*)&xs[c][t0];
        *(float4*)&a[4]  = *(const float4*)&xs[c][t0 + 4];
        *(float4*)&wv[0] = *(const float4*)&w2s[c][o0];
        *(float4*)&wv[4] = *(const float4*)&w2s[c][o0 + 4];
#pragma unroll
        for (int i = 0; i < 8; ++i)
#pragma unroll
            for (int jj = 0; jj < 8; ++jj)
                acc[i][jj] = fmaf(a[i], wv[jj], acc[i][jj]);
    }

#pragma unroll
    for (int i = 0; i < 8; ++i) {
        f16x8v hv;
#pragma unroll
        for (int jj = 0; jj < 8; ++jj) hv[jj] = (_Float16)acc[i][jj];
        *(f16x8v*)&i2sh[((size_t)(b * WW + (t0 + i)) * HH + row) * OCH + o0] = hv;
    }
}

// ===== K2 v11: SINGLE-WAVE step, zero barriers. M=16 MFMA tiling makes each
// lane's D-frag hold the 4 gates of its own cells -> cell math is pure-register.
// W1 = 64 B-frag VGPRs loaded once; i2s enters as MFMA C-init (global, 1-deep
// prefetch); h state lives in f16 LDS (phs) with wave-internal lgkmcnt only.
__global__ __launch_bounds__(64, 1) void diag_lstm_scan_v11(
    const float* __restrict__ W1g, float* __restrict__ out,
    int* __restrict__ progress, unsigned long long* __restrict__ hand,
    const _Float16* __restrict__ i2sh)
{
    const int l   = threadIdx.x;       // 0..63
    const int blk = blockIdx.x;
    const int b   = blk & 15;          // chain (b, k=0..7) strides 16 -> same XCD
    const int k   = blk >> 4;          // 0..7
    const int q   = l >> 4;            // row quad 0..3
    const int col = l & 15;            // MFMA m/n/col index

    __shared__ _Float16 phs[2][17][40];   // [par][row 0..16][c], pad 40 (2-way max)
    for (int i = l; i < 2 * 17 * 40; i += 64) (&phs[0][0][0])[i] = (_Float16)0.f;

    // ---- B-frags: bw[nt][h], B[n=col][kk=8q+e] = W1[o=16nt+col][32h+8q+e] ----
    f16x8v bw[8][2];
#pragma unroll
    for (int nt = 0; nt < 8; ++nt) {
        const int o = nt * 16 + col;
#pragma unroll
        for (int h = 0; h < 2; ++h) {
            const float4 w0 = *(const float4*)&W1g[(size_t)o * 64 + 32 * h + 8 * q];
            const float4 w1 = *(const float4*)&W1g[(size_t)o * 64 + 32 * h + 8 * q + 4];
            f16x8v v;
            v[0] = (_Float16)w0.x; v[1] = (_Float16)w0.y;
            v[2] = (_Float16)w0.z; v[3] = (_Float16)w0.w;
            v[4] = (_Float16)w1.x; v[5] = (_Float16)w1.y;
            v[6] = (_Float16)w1.z; v[7] = (_Float16)w1.w;
            bw[nt][h] = v;
        }
    }

    // ---- i2s per-lane prefetch (1-deep): u[nt][e] = i2s[t][k16+4q+e][16nt+col]
    const ushort* i2su = (const ushort*)i2sh;
    ushort u[8][4];
    {
        const size_t base = ((size_t)(b * WW + 0) * HH + k * 16 + 4 * q) * OCH + col;
#pragma unroll
        for (int nt = 0; nt < 8; ++nt)
#pragma unroll
            for (int e = 0; e < 4; ++e)
                u[nt][e] = i2su[base + (size_t)e * OCH + nt * 16];
    }

    // ---- cell state: 8 cells/lane: (r = 4q+e, j = col+16v) ----
    float pc[2][4], ob0[2][4], ob1[2][4], ob2[2][4];
#pragma unroll
    for (int v = 0; v < 2; ++v)
#pragma unroll
        for (int e = 0; e < 4; ++e) { pc[v][e] = 0.f; ob0[v][e] = 0.f; ob1[v][e] = 0.f; ob2[v][e] = 0.f; }

    // ---- ring handoff ----
    const int kprev = (k > 0) ? k - 1 : 0;
    const unsigned long long* srcring =
        hand + ((size_t)(b * NCH + kprev) * DEPTH) * BO + l;        // lane ch = l (<32)
    unsigned long long* dstring =
        hand + ((size_t)(b * NCH + k) * DEPTH) * BO + col;          // +16v at store
    int* myprog   = progress + (b * NCH + k);
    int* consprog = myprog + 1;
    unsigned long long pre = 0ull;

    for (int t = 0; t < WW; ++t) {
        _Float16 (*PS)[40] = phs[t & 1];
        _Float16 (*PD)[40] = phs[(t & 1) ^ 1];

        // ---- boundary poll (lanes < 32; value tag t at slot (t-1)&63) ----
        if (k > 0 && t > 0) {
            unsigned long long qv = pre;
            while (__any(l < 32 && (unsigned)(qv >> 32) != (unsigned)t)) {
                if (l < 32)
                    qv = __hip_atomic_load(&srcring[(size_t)((t - 1) & 63) * BO],
                                           __ATOMIC_RELAXED, __HIP_MEMORY_SCOPE_AGENT);
            }
            if (l < 32) {
                PS[0][l] = (_Float16)__uint_as_float((unsigned)qv);
                pre = __hip_atomic_load(&srcring[(size_t)(t & 63) * BO],
                                        __ATOMIC_RELAXED, __HIP_MEMORY_SCOPE_AGENT);
            }
        }

        // ---- A-frags: A[m=col][kk] ; af0: c=4q+(e>>1), af1: c=16+4q+(e>>1),
        //      which=e&1 -> interleave rows m (boundary-aware) and m+1 ----
        const f16x4v r0 = *(const f16x4v*)&PS[col][4 * q];
        const f16x4v r1 = *(const f16x4v*)&PS[col + 1][4 * q];
        const f16x4v r2 = *(const f16x4v*)&PS[col][16 + 4 * q];
        const f16x4v r3 = *(const f16x4v*)&PS[col + 1][16 + 4 * q];
        f16x8v af0, af1;
        af0[0] = r0[0]; af0[1] = r1[0]; af0[2] = r0[1]; af0[3] = r1[1];
        af0[4] = r0[2]; af0[5] = r1[2]; af0[6] = r0[3]; af0[7] = r1[3];
        af1[0] = r2[0]; af1[1] = r3[0]; af1[2] = r2[1]; af1[3] = r3[1];
        af1[4] = r2[2]; af1[5] = r3[2]; af1[6] = r2[3]; af1[7] = r3[3];

        // ---- acc init from i2s (C-input), then refill prefetch for t+1 ----
        f32x4v acc[8];
#pragma unroll
        for (int nt = 0; nt < 8; ++nt) {
#pragma unroll
            for (int e = 0; e < 4; ++e) {
                ushort uv = u[nt][e];
                acc[nt][e] = (float)(*reinterpret_cast<const _Float16*>(&uv));
            }
        }
        {
            const int tn = (t + 1 < WW) ? t + 1 : WW - 1;
            const size_t base = ((size_t)(b * WW + tn) * HH + k * 16 + 4 * q) * OCH + col;
#pragma unroll
            for (int nt = 0; nt < 8; ++nt)
#pragma unroll
                for (int e = 0; e < 4; ++e)
                    u[nt][e] = i2su[base + (size_t)e * OCH + nt * 16];
        }

        // ---- 16 MFMAs: gates = W1 · [h_prev; h_cur] + i2s ----
#pragma unroll
        for (int nt = 0; nt < 8; ++nt) {
            acc[nt] = __builtin_amdgcn_mfma_f32_16x16x32_f16(af0, bw[nt][0], acc[nt], 0, 0, 0);
            acc[nt] = __builtin_amdgcn_mfma_f32_16x16x32_f16(af1, bw[nt][1], acc[nt], 0, 0, 0);
        }

        // ---- back-pressure (whole wave held by lane-0 spin) ----
        if (k < NCH - 1 && (t & 15) == 0 && t >= 48 && l == 0) {
            while (__hip_atomic_load(consprog, __ATOMIC_RELAXED,
                                     __HIP_MEMORY_SCOPE_AGENT) < t - 47) { }
        }

        // ---- cell update: all register-local (D-frag alignment) ----
#pragma unroll
        for (int v = 0; v < 2; ++v) {
#pragma unroll
            for (int e = 0; e < 4; ++e) {
                const float go = acc[v][e];
                const float gf = acc[v + 2][e];
                const float gi = acc[v + 4][e];
                const float gg = acc[v + 6][e];
                const float so = 1.f / (1.f + __expf(-go));
                const float sf = 1.f / (1.f + __expf(-gf));
                const float si = 1.f / (1.f + __expf(-gi));
                const float tg = 2.f / (1.f + __expf(-2.f * gg)) - 1.f;
                const float nc = sf * pc[v][e] + si * tg;
                const float th = 2.f / (1.f + __expf(-2.f * nc)) - 1.f;
                const float nh = so * th;
                pc[v][e] = nc;
                PD[4 * q + e + 1][col + 16 * v] = (_Float16)nh;

                const int ph4 = t & 3;
                if (ph4 == 0)      ob0[v][e] = nh;
                else if (ph4 == 1) ob1[v][e] = nh;
                else if (ph4 == 2) ob2[v][e] = nh;
                else {
                    *(float4*)(out + ((size_t)(b * BO + col + 16 * v) * HH
                                      + k * RPC + 4 * q + e) * WW + (t - 3))
                        = make_float4(ob0[v][e], ob1[v][e], ob2[v][e], nh);
                }

                if (q == 3 && e == 3 && k < NCH - 1) {   // r==15: handoff
                    unsigned long long qq =
                        ((unsigned long long)(unsigned)(t + 1) << 32)
                      | (unsigned long long)__float_as_uint(nh);
                    __hip_atomic_store(&dstring[(size_t)(t & 63) * BO + 16 * v], qq,
                                       __ATOMIC_RELAXED, __HIP_MEMORY_SCOPE_AGENT);
                }
            }
        }
        if (l == 0) {
            __hip_atomic_store(myprog, t + 1, __ATOMIC_RELAXED,
                               __HIP_MEMORY_SCOPE_AGENT);
        }
    }
}

// ===================== fallback (R4, proven, ws-lean) =====================
__global__ __launch_bounds__(512, 2) void diag_lstm_scan_v4(
    const float* __restrict__ x, const float* __restrict__ W2g,
    const float* __restrict__ b2, const float* __restrict__ W1g,
    const float* __restrict__ b1, float* __restrict__ out,
    int* __restrict__ progress, unsigned long long* __restrict__ hand)
{
    const int tid = threadIdx.x;
    const int l   = tid & 63;
    const int w   = tid >> 6;
    const int blk = blockIdx.x;
    const int b = (blk & 7) + ((blk >> 7) << 3);
    const int k = (blk >> 3) & 15;
    const int row = k * 8 + w;

    __shared__ __attribute__((aligned(16))) float phs[2][9][BO];
    __shared__ __attribute__((aligned(16))) float xbuf[8][CIN];
    __shared__ __attribute__((aligned(16))) float gbuf2[8][OCH];

    for (int i = tid; i < 2 * 9 * BO; i += 512) ((float*)phs)[i] = 0.f;

    const int o0 = 2 * l, o1 = 2 * l + 1;
    float w2a[CIN], w2b[CIN], w1pa[CIN], w1ca[CIN], w1pb[CIN], w1cb[CIN];
#pragma unroll
    for (int c = 0; c < CIN; ++c) {
        w2a[c]  = W2g[o0 * CIN + c];
        w2b[c]  = W2g[o1 * CIN + c];
        w1pa[c] = W1g[(o0 * CIN + c) * 2 + 0];
        w1ca[c] = W1g[(o0 * CIN + c) * 2 + 1];
        w1pb[c] = W1g[(o1 * CIN + c) * 2 + 0];
        w1cb[c] = W1g[(o1 * CIN + c) * 2 + 1];
    }
    const float biasA = b2[o0] + b1[o0];
    const float biasB = b2[o1] + b1[o1];

    const int j = l & 31;
    float pc = 0.f, ob0 = 0.f, ob1 = 0.f, ob2 = 0.f;
    float* outrow = out + ((size_t)(b * BO + j) * HH + row) * WW;

    const int kprev = (k > 0) ? k - 1 : 0;
    const unsigned long long* srcbase =
        hand + (size_t)((b * 16 + kprev) * DEPTH) * BO + j;
    unsigned long long* dstbase =
        hand + (size_t)((b * 16 + k) * DEPTH) * BO + j;
    int* myprog   = progress + (b * 16 + k);
    int* consprog = myprog + 1;

    unsigned long long pre = 0ull;
    __syncthreads();

    for (int t = 0; t < WW; ++t) {
        const int par = t & 1;
        if (l < 32) {
            const int wp = t - row;
            xbuf[w][l] = (wp >= 0)
                ? x[((size_t)(b * CIN + l) * HH + row) * WW + wp] : 0.f;
        }
        if (w == 0 && k > 0) {
            if (t > 0) {
                unsigned long long q = pre;
                while (__any((unsigned)(q >> 32) != (unsigned)t)) {
                    q = __hip_atomic_load(&srcbase[(size_t)((t - 1) & (DEPTH - 1)) * BO],
                                          __ATOMIC_RELAXED, __HIP_MEMORY_SCOPE_AGENT);
                }
                if (l < 32) phs[par][0][l] = __uint_as_float((unsigned)q);
            }
            pre = __hip_atomic_load(&srcbase[(size_t)(t & (DEPTH - 1)) * BO],
                                    __ATOMIC_RELAXED, __HIP_MEMORY_SCOPE_AGENT);
        }
        asm volatile("s_waitcnt lgkmcnt(0)" ::: "memory");

        float ga = biasA, gb = biasB;
        {
            const float4* xb4 = (const float4*)(&xbuf[w][0]);
            const float4* pv4 = (const float4*)(&phs[par][w][0]);
            const float4* qv4 = (const float4*)(&phs[par][w + 1][0]);
#pragma unroll
            for (int cc = 0; cc < CIN / 4; ++cc) {
                const float4 xv = xb4[cc];
                const float4 pv = pv4[cc];
                const float4 qv = qv4[cc];
                const float* xs = (const float*)&xv;
                const float* ps = (const float*)&pv;
                const float* qs = (const float*)&qv;
#pragma unroll
                for (int ci = 0; ci < 4; ++ci) {
                    const int c = 4 * cc + ci;
                    ga = fmaf(w2a[c],  xs[ci], ga);
                    gb = fmaf(w2b[c],  xs[ci], gb);
                    ga = fmaf(w1pa[c], ps[ci], ga);
                    gb = fmaf(w1pb[c], ps[ci], gb);
                    ga = fmaf(w1ca[c], qs[ci], ga);
                    gb = fmaf(w1cb[c], qs[ci], gb);
                }
            }
        }
        *(float2*)&gbuf2[w][o0] = make_float2(ga, gb);
        asm volatile("s_waitcnt lgkmcnt(0)" ::: "memory");

        if (l < 32) {
            if (w == 7 && k < 15 && (t & 15) == 0 && t >= 48) {
                while (__hip_atomic_load(consprog, __ATOMIC_RELAXED,
                                         __HIP_MEMORY_SCOPE_AGENT) < t - 47) { }
            }
            const float go = gbuf2[w][l];
            const float gf = gbuf2[w][32 + l];
            const float gi = gbuf2[w][64 + l];
            const float gg = gbuf2[w][96 + l];
            const float so = 1.f / (1.f + __expf(-go));
            const float sf = 1.f / (1.f + __expf(-gf));
            const float si = 1.f / (1.f + __expf(-gi));
            const float tg = 2.f / (1.f + __expf(-2.f * gg)) - 1.f;
            const float nc = sf * pc + si * tg;
            const float th = 2.f / (1.f + __expf(-2.f * nc)) - 1.f;
            const float nh = so * th;
            pc = nc;
            phs[par ^ 1][w + 1][l] = nh;

            const int ph4 = t & 3;
            if (ph4 == 0) ob0 = nh;
            else if (ph4 == 1) ob1 = nh;
            else if (ph4 == 2) ob2 = nh;
            else *(float4*)(outrow + (t - 3)) = make_float4(ob0, ob1, ob2, nh);

            if (w == 7 && k < 15) {
                unsigned long long q = ((unsigned long long)(unsigned)(t + 1) << 32)
                                     | (unsigned long long)__float_as_uint(nh);
                __hip_atomic_store(&dstbase[(size_t)(t & (DEPTH - 1)) * BO], q,
                                   __ATOMIC_RELAXED, __HIP_MEMORY_SCOPE_AGENT);
            }
            if (w == 0 && l == 0) {
                __hip_atomic_store(myprog, t + 1, __ATOMIC_RELAXED,
                                   __HIP_MEMORY_SCOPE_AGENT);
            }
        }
        __syncthreads();
    }
}

extern "C" void kernel_launch(void* const* d_in, const int* in_sizes, int n_in,
                              void* d_out, int out_size, void* d_ws, size_t ws_size,
                              hipStream_t stream) {
    const float* x  = (const float*)d_in[0];
    const float* W2 = (const float*)d_in[1];
    const float* b2 = (const float*)d_in[2];
    const float* W1 = (const float*)d_in[3];
    const float* b1 = (const float*)d_in[4];
    float* out = (float*)d_out;

    int* progress = (int*)d_ws;
    unsigned long long* hand = (unsigned long long*)((char*)d_ws + 4096);
    _Float16* i2sh = (_Float16*)((char*)d_ws + 4096 + RINGSZ);

    const size_t need = 4096 + RINGSZ + I2SHSZ;

    hipMemsetAsync(d_ws, 0, 4096 + RINGSZ, stream);

    if (ws_size >= need) {
        hipLaunchKernelGGL(i2s_gemm_h, dim3(BATCH * HH), dim3(256), 0, stream,
                           x, W2, b2, b1, i2sh);
        hipLaunchKernelGGL(diag_lstm_scan_v11, dim3(BATCH * NCH), dim3(64), 0, stream,
                           W1, out, progress, hand, i2sh);
    } else {
        // fallback ring uses 16-chunk layout; still fits RINGSZ (8-chunk) * 2?
        // no — v4 uses BATCH*16*DEPTH*BO entries = 2x RINGSZ. Clear its range too.
        hipMemsetAsync(d_ws, 0, 4096 + (size_t)BATCH * 16 * DEPTH * BO * 8, stream);
        hipLaunchKernelGGL(diag_lstm_scan_v4, dim3(BATCH * 16), dim3(512), 0, stream,
                           x, W2, b2, W1, b1, out, progress, hand);
    }
}

// Round 12
// 251.086 us; speedup vs baseline: 1.6728x; 1.6728x over previous
//
#include <hip/hip_runtime.h>
#include <stdint.h>

#define BATCH 16
#define CIN   32
#define HH    128
#define WW    128
#define BO    32
#define OCH   128   // 4*BO
#define NCH   4     // h-chunks (32 rows each)
#define RPC   32
#define DEPTH 64    // handoff ring depth

// ws: [0,4096) progress ints
//     [4096, +RINGMAX) tagged handoff ring (sized for fallback's 16 chunks)
//     [4096+RINGMAX, +I2SHSZ) i2s buffer (f16, layout [b][t][row][o])
#define RINGMAX ((size_t)BATCH * 16 * DEPTH * BO * 8)
#define I2SHSZ  ((size_t)BATCH * WW * HH * OCH * 2)

typedef _Float16 f16x4v __attribute__((ext_vector_type(4)));
typedef _Float16 f16x8v __attribute__((ext_vector_type(8)));
typedef float    f32x4v __attribute__((ext_vector_type(4)));

// ===== K1: i2s_h[b][t][row][o] = (f16)(b2+b1 + sum_c W2[o][c]*xskew) ========
__global__ __launch_bounds__(256, 4) void i2s_gemm_h(
    const float* __restrict__ x, const float* __restrict__ W2g,
    const float* __restrict__ b2, const float* __restrict__ b1,
    _Float16* __restrict__ i2sh)
{
    const int tid = threadIdx.x;
    const int bx  = blockIdx.x;
    const int b   = bx >> 7;
    const int row = bx & 127;

    __shared__ __attribute__((aligned(16))) float xs[CIN][WW];
    __shared__ __attribute__((aligned(16))) float w2s[CIN][OCH];
    __shared__ float bs[OCH];

    for (int i = tid; i < CIN * OCH; i += 256) {
        const int c = i >> 7, o = i & 127;
        w2s[c][o] = W2g[o * CIN + c];
    }
    if (tid < OCH) bs[tid] = b2[tid] + b1[tid];
    for (int i = tid; i < CIN * WW; i += 256) {
        const int c = i >> 7, t = i & 127;
        xs[c][t] = (t >= row)
            ? x[((size_t)(b * CIN + c) * HH + row) * WW + (t - row)] : 0.f;
    }
    __syncthreads();

    const int tm = tid >> 4;
    const int tn = tid & 15;
    const int t0 = tm * 8, o0 = tn * 8;

    float bv[8];
    *(float4*)&bv[0] = *(const float4*)&bs[o0];
    *(float4*)&bv[4] = *(const float4*)&bs[o0 + 4];
    float acc[8][8];
#pragma unroll
    for (int i = 0; i < 8; ++i)
#pragma unroll
        for (int jj = 0; jj < 8; ++jj) acc[i][jj] = bv[jj];

    for (int c = 0; c < CIN; ++c) {
        float a[8], wv[8];
        *(float4*)&a[0]  = *(const float4*)&xs[c][t0];
        *(float4*)&a[4]  = *(const float4*)&xs[c][t0 + 4];
        *(float4*)&wv[0] = *(const float4*)&w2s[c][o0];
        *(float4*)&wv[4] = *(const float4*)&w2s[c][o0 + 4];
#pragma unroll
        for (int i = 0; i < 8; ++i)
#pragma unroll
            for (int jj = 0; jj < 8; ++jj)
                acc[i][jj] = fmaf(a[i], wv[jj], acc[i][jj]);
    }

#pragma unroll
    for (int i = 0; i < 8; ++i) {
        f16x8v hv;
#pragma unroll
        for (int jj = 0; jj < 8; ++jj) hv[jj] = (_Float16)acc[i][jj];
        *(f16x8v*)&i2sh[((size_t)(b * WW + (t0 + i)) * HH + row) * OCH + o0] = hv;
    }
}

// ===== K2 v12: 4 waves/block, 32-row chunk, register-local cells, 1 barrier.
// Wave (m,p): M-tile m (rows 16m..16m+15), N-tiles {p,p+2,p+4,p+6} -> 8 MFMAs,
// bw = 32 VGPRs (v10-scale, below the observed ~100-VGPR sink threshold that
// killed v11's 64-reg version). Cells j=16p+col fully register-local.
__global__ __launch_bounds__(256) void diag_lstm_scan_v12(
    const float* __restrict__ W1g, float* __restrict__ out,
    int* __restrict__ progress, unsigned long long* __restrict__ hand,
    const _Float16* __restrict__ i2sh)
{
    const int tid = threadIdx.x;
    const int l   = tid & 63;
    const int w   = tid >> 6;       // wave 0..3
    const int m   = w >> 1;         // M-tile 0..1
    const int p   = w & 1;          // N-parity
    const int q   = l >> 4;         // 0..3
    const int col = l & 15;
    const int blk = blockIdx.x;
    const int b   = blk & 15;       // chain (b, k=0..3) strides 16 -> same XCD
    const int k   = blk >> 4;       // 0..3

    __shared__ _Float16 phs[2][33][40];   // [par][row 0..32][ch], pad 40
    for (int i = tid; i < 2 * 33 * 40; i += 256) (&phs[0][0][0])[i] = (_Float16)0.f;

    // ---- B-frags: bw[s][h]; N-tile nt=p+2s; B[n=col][kk=8q+e]=W1[o][32h+8q+e]
    f16x8v bw[4][2];
#pragma unroll
    for (int s = 0; s < 4; ++s) {
        const int o = (p + 2 * s) * 16 + col;
#pragma unroll
        for (int h = 0; h < 2; ++h) {
            const float4 w0 = *(const float4*)&W1g[(size_t)o * 64 + 32 * h + 8 * q];
            const float4 w1 = *(const float4*)&W1g[(size_t)o * 64 + 32 * h + 8 * q + 4];
            f16x8v v;
            v[0] = (_Float16)w0.x; v[1] = (_Float16)w0.y;
            v[2] = (_Float16)w0.z; v[3] = (_Float16)w0.w;
            v[4] = (_Float16)w1.x; v[5] = (_Float16)w1.y;
            v[6] = (_Float16)w1.z; v[7] = (_Float16)w1.w;
            bw[s][h] = v;
        }
    }

    // ---- i2s per-lane prefetch (1-deep): u[s][e] for row 32k+16m+4q+e,
    //      channel 16(p+2s)+col = (16p+col) + 32s
    const ushort* i2su = (const ushort*)i2sh;
    const int j = 16 * p + col;
    const int grow0 = k * RPC + 16 * m + 4 * q;      // global row for e=0
    ushort u[4][4];
    {
        const size_t base = ((size_t)(b * WW + 0) * HH + grow0) * OCH + j;
#pragma unroll
        for (int s = 0; s < 4; ++s)
#pragma unroll
            for (int e = 0; e < 4; ++e)
                u[s][e] = i2su[base + (size_t)e * OCH + 32 * s];
    }

    float pc[4] = {0.f, 0.f, 0.f, 0.f};

    // ---- ring handoff ----
    const int kprev = (k > 0) ? k - 1 : 0;
    const unsigned long long* srcring =
        hand + ((size_t)(b * NCH + kprev) * DEPTH) * BO + l;   // poll ch = l (<32)
    unsigned long long* dstring =
        hand + ((size_t)(b * NCH + k) * DEPTH) * BO + j;
    int* myprog   = progress + (b * NCH + k);
    int* consprog = myprog + 1;
    unsigned long long pre = 0ull;

    __syncthreads();

    for (int t = 0; t < WW; ++t) {
        _Float16 (*PS)[40] = phs[t & 1];
        _Float16 (*PD)[40] = phs[(t & 1) ^ 1];

        // ---- boundary poll: BOTH m=0 waves redundantly (idempotent) ----
        if (m == 0 && k > 0 && t > 0) {
            unsigned long long qv = pre;
            while (__any(l < 32 && (unsigned)(qv >> 32) != (unsigned)t)) {
                if (l < 32)
                    qv = __hip_atomic_load(&srcring[(size_t)((t - 1) & 63) * BO],
                                           __ATOMIC_RELAXED, __HIP_MEMORY_SCOPE_AGENT);
            }
            if (l < 32) {
                PS[0][l] = (_Float16)__uint_as_float((unsigned)qv);
                pre = __hip_atomic_load(&srcring[(size_t)(t & 63) * BO],
                                        __ATOMIC_RELAXED, __HIP_MEMORY_SCOPE_AGENT);
            }
        }

        // ---- A-frags (v11-verified layout): rows 16m+col / 16m+col+1 ----
        const f16x4v r0 = *(const f16x4v*)&PS[16 * m + col][4 * q];
        const f16x4v r1 = *(const f16x4v*)&PS[16 * m + col + 1][4 * q];
        const f16x4v r2 = *(const f16x4v*)&PS[16 * m + col][16 + 4 * q];
        const f16x4v r3 = *(const f16x4v*)&PS[16 * m + col + 1][16 + 4 * q];
        f16x8v af0, af1;
        af0[0] = r0[0]; af0[1] = r1[0]; af0[2] = r0[1]; af0[3] = r1[1];
        af0[4] = r0[2]; af0[5] = r1[2]; af0[6] = r0[3]; af0[7] = r1[3];
        af1[0] = r2[0]; af1[1] = r3[0]; af1[2] = r2[1]; af1[3] = r3[1];
        af1[4] = r2[2]; af1[5] = r3[2]; af1[6] = r2[3]; af1[7] = r3[3];

        // ---- acc init from i2s (C-input), refill prefetch for t+1 ----
        f32x4v acc[4];
#pragma unroll
        for (int s = 0; s < 4; ++s)
#pragma unroll
            for (int e = 0; e < 4; ++e) {
                ushort uv = u[s][e];
                acc[s][e] = (float)(*reinterpret_cast<const _Float16*>(&uv));
            }
        {
            const int tn = (t + 1 < WW) ? t + 1 : WW - 1;
            const size_t base = ((size_t)(b * WW + tn) * HH + grow0) * OCH + j;
#pragma unroll
            for (int s = 0; s < 4; ++s)
#pragma unroll
                for (int e = 0; e < 4; ++e)
                    u[s][e] = i2su[base + (size_t)e * OCH + 32 * s];
        }

        // ---- 8 MFMAs ----
#pragma unroll
        for (int s = 0; s < 4; ++s) {
            acc[s] = __builtin_amdgcn_mfma_f32_16x16x32_f16(af0, bw[s][0], acc[s], 0, 0, 0);
            acc[s] = __builtin_amdgcn_mfma_f32_16x16x32_f16(af1, bw[s][1], acc[s], 0, 0, 0);
        }

        // ---- back-pressure: stall the handoff-writing waves only ----
        if (m == 1 && k < NCH - 1 && l == 0 && (t & 15) == 0 && t >= 48) {
            while (__hip_atomic_load(consprog, __ATOMIC_RELAXED,
                                     __HIP_MEMORY_SCOPE_AGENT) < t - 39) { }
        }

        // ---- cells: 4/lane, all register-local ----
#pragma unroll
        for (int e = 0; e < 4; ++e) {
            const float go = acc[0][e];
            const float gf = acc[1][e];
            const float gi = acc[2][e];
            const float gg = acc[3][e];
            const float so = 1.f / (1.f + __expf(-go));
            const float sf = 1.f / (1.f + __expf(-gf));
            const float si = 1.f / (1.f + __expf(-gi));
            const float tg = 2.f / (1.f + __expf(-2.f * gg)) - 1.f;
            const float nc = sf * pc[e] + si * tg;
            const float th = 2.f / (1.f + __expf(-2.f * nc)) - 1.f;
            const float nh = so * th;
            pc[e] = nc;
            PD[16 * m + 4 * q + e + 1][j] = (_Float16)nh;

            out[((size_t)(b * BO + j) * HH + (grow0 + e)) * WW + t] = nh;

            if (m == 1 && q == 3 && e == 3 && k < NCH - 1) {   // local row 31
                unsigned long long qq =
                    ((unsigned long long)(unsigned)(t + 1) << 32)
                  | (unsigned long long)__float_as_uint(nh);
                __hip_atomic_store(&dstring[(size_t)(t & 63) * BO], qq,
                                   __ATOMIC_RELAXED, __HIP_MEMORY_SCOPE_AGENT);
            }
        }
        if (tid == 0) {
            __hip_atomic_store(myprog, t + 1, __ATOMIC_RELAXED,
                               __HIP_MEMORY_SCOPE_AGENT);
        }
        __syncthreads();   // publish PD (and next step's PS[0] usage ordering)
    }
}

// ===================== fallback (R4, proven, ws-lean) =====================
__global__ __launch_bounds__(512, 2) void diag_lstm_scan_v4(
    const float* __restrict__ x, const float* __restrict__ W2g,
    const float* __restrict__ b2, const float* __restrict__ W1g,
    const float* __restrict__ b1, float* __restrict__ out,
    int* __restrict__ progress, unsigned long long* __restrict__ hand)
{
    const int tid = threadIdx.x;
    const int l   = tid & 63;
    const int w   = tid >> 6;
    const int blk = blockIdx.x;
    const int b = (blk & 7) + ((blk >> 7) << 3);
    const int k = (blk >> 3) & 15;
    const int row = k * 8 + w;

    __shared__ __attribute__((aligned(16))) float phs[2][9][BO];
    __shared__ __attribute__((aligned(16))) float xbuf[8][CIN];
    __shared__ __attribute__((aligned(16))) float gbuf2[8][OCH];

    for (int i = tid; i < 2 * 9 * BO; i += 512) ((float*)phs)[i] = 0.f;

    const int o0 = 2 * l, o1 = 2 * l + 1;
    float w2a[CIN], w2b[CIN], w1pa[CIN], w1ca[CIN], w1pb[CIN], w1cb[CIN];
#pragma unroll
    for (int c = 0; c < CIN; ++c) {
        w2a[c]  = W2g[o0 * CIN + c];
        w2b[c]  = W2g[o1 * CIN + c];
        w1pa[c] = W1g[(o0 * CIN + c) * 2 + 0];
        w1ca[c] = W1g[(o0 * CIN + c) * 2 + 1];
        w1pb[c] = W1g[(o1 * CIN + c) * 2 + 0];
        w1cb[c] = W1g[(o1 * CIN + c) * 2 + 1];
    }
    const float biasA = b2[o0] + b1[o0];
    const float biasB = b2[o1] + b1[o1];

    const int j = l & 31;
    float pc = 0.f, ob0 = 0.f, ob1 = 0.f, ob2 = 0.f;
    float* outrow = out + ((size_t)(b * BO + j) * HH + row) * WW;

    const int kprev = (k > 0) ? k - 1 : 0;
    const unsigned long long* srcbase =
        hand + (size_t)((b * 16 + kprev) * DEPTH) * BO + j;
    unsigned long long* dstbase =
        hand + (size_t)((b * 16 + k) * DEPTH) * BO + j;
    int* myprog   = progress + (b * 16 + k);
    int* consprog = myprog + 1;

    unsigned long long pre = 0ull;
    __syncthreads();

    for (int t = 0; t < WW; ++t) {
        const int par = t & 1;
        if (l < 32) {
            const int wp = t - row;
            xbuf[w][l] = (wp >= 0)
                ? x[((size_t)(b * CIN + l) * HH + row) * WW + wp] : 0.f;
        }
        if (w == 0 && k > 0) {
            if (t > 0) {
                unsigned long long q = pre;
                while (__any((unsigned)(q >> 32) != (unsigned)t)) {
                    q = __hip_atomic_load(&srcbase[(size_t)((t - 1) & (DEPTH - 1)) * BO],
                                          __ATOMIC_RELAXED, __HIP_MEMORY_SCOPE_AGENT);
                }
                if (l < 32) phs[par][0][l] = __uint_as_float((unsigned)q);
            }
            pre = __hip_atomic_load(&srcbase[(size_t)(t & (DEPTH - 1)) * BO],
                                    __ATOMIC_RELAXED, __HIP_MEMORY_SCOPE_AGENT);
        }
        asm volatile("s_waitcnt lgkmcnt(0)" ::: "memory");

        float ga = biasA, gb = biasB;
        {
            const float4* xb4 = (const float4*)(&xbuf[w][0]);
            const float4* pv4 = (const float4*)(&phs[par][w][0]);
            const float4* qv4 = (const float4*)(&phs[par][w + 1][0]);
#pragma unroll
            for (int cc = 0; cc < CIN / 4; ++cc) {
                const float4 xv = xb4[cc];
                const float4 pv = pv4[cc];
                const float4 qv = qv4[cc];
                const float* xs = (const float*)&xv;
                const float* ps = (const float*)&pv;
                const float* qs = (const float*)&qv;
#pragma unroll
                for (int ci = 0; ci < 4; ++ci) {
                    const int c = 4 * cc + ci;
                    ga = fmaf(w2a[c],  xs[ci], ga);
                    gb = fmaf(w2b[c],  xs[ci], gb);
                    ga = fmaf(w1pa[c], ps[ci], ga);
                    gb = fmaf(w1pb[c], ps[ci], gb);
                    ga = fmaf(w1ca[c], qs[ci], ga);
                    gb = fmaf(w1cb[c], qs[ci], gb);
                }
            }
        }
        *(float2*)&gbuf2[w][o0] = make_float2(ga, gb);
        asm volatile("s_waitcnt lgkmcnt(0)" ::: "memory");

        if (l < 32) {
            if (w == 7 && k < 15 && (t & 15) == 0 && t >= 48) {
                while (__hip_atomic_load(consprog, __ATOMIC_RELAXED,
                                         __HIP_MEMORY_SCOPE_AGENT) < t - 47) { }
            }
            const float go = gbuf2[w][l];
            const float gf = gbuf2[w][32 + l];
            const float gi = gbuf2[w][64 + l];
            const float gg = gbuf2[w][96 + l];
            const float so = 1.f / (1.f + __expf(-go));
            const float sf = 1.f / (1.f + __expf(-gf));
            const float si = 1.f / (1.f + __expf(-gi));
            const float tg = 2.f / (1.f + __expf(-2.f * gg)) - 1.f;
            const float nc = sf * pc + si * tg;
            const float th = 2.f / (1.f + __expf(-2.f * nc)) - 1.f;
            const float nh = so * th;
            pc = nc;
            phs[par ^ 1][w + 1][l] = nh;

            const int ph4 = t & 3;
            if (ph4 == 0) ob0 = nh;
            else if (ph4 == 1) ob1 = nh;
            else if (ph4 == 2) ob2 = nh;
            else *(float4*)(outrow + (t - 3)) = make_float4(ob0, ob1, ob2, nh);

            if (w == 7 && k < 15) {
                unsigned long long q = ((unsigned long long)(unsigned)(t + 1) << 32)
                                     | (unsigned long long)__float_as_uint(nh);
                __hip_atomic_store(&dstbase[(size_t)(t & (DEPTH - 1)) * BO], q,
                                   __ATOMIC_RELAXED, __HIP_MEMORY_SCOPE_AGENT);
            }
            if (w == 0 && l == 0) {
                __hip_atomic_store(myprog, t + 1, __ATOMIC_RELAXED,
                                   __HIP_MEMORY_SCOPE_AGENT);
            }
        }
        __syncthreads();
    }
}

extern "C" void kernel_launch(void* const* d_in, const int* in_sizes, int n_in,
                              void* d_out, int out_size, void* d_ws, size_t ws_size,
                              hipStream_t stream) {
    const float* x  = (const float*)d_in[0];
    const float* W2 = (const float*)d_in[1];
    const float* b2 = (const float*)d_in[2];
    const float* W1 = (const float*)d_in[3];
    const float* b1 = (const float*)d_in[4];
    float* out = (float*)d_out;

    int* progress = (int*)d_ws;
    unsigned long long* hand = (unsigned long long*)((char*)d_ws + 4096);
    _Float16* i2sh = (_Float16*)((char*)d_ws + 4096 + RINGMAX);

    const size_t need = 4096 + RINGMAX + I2SHSZ;

    // clear progress + full ring region (covers both v12's and fallback's layouts)
    hipMemsetAsync(d_ws, 0, 4096 + RINGMAX, stream);

    if (ws_size >= need) {
        hipLaunchKernelGGL(i2s_gemm_h, dim3(BATCH * HH), dim3(256), 0, stream,
                           x, W2, b2, b1, i2sh);
        hipLaunchKernelGGL(diag_lstm_scan_v12, dim3(BATCH * NCH), dim3(256), 0, stream,
                           W1, out, progress, hand, i2sh);
    } else {
        hipLaunchKernelGGL(diag_lstm_scan_v4, dim3(BATCH * 16), dim3(512), 0, stream,
                           x, W2, b2, W1, b1, out, progress, hand);
    }
}